// Round 6
// baseline (343.465 us; speedup 1.0000x reference)
//
#include <hip/hip_runtime.h>
#include <hip/hip_bf16.h>
#include <math.h>

#define VOCAB 100000
#define EMB 100
#define HID 100
#define CTX_LEN 60
#define FACT_LEN 20
#define DESC_LEN 60
#define NCHUNK (VOCAB / 16)   // 6250 column chunks of 16
#define NWLOG  1275           // logits waves: 255 blocks x 5 waves
#define MSSTRIDE 1280

// workspace layout (float offsets)
#define WS_FACTS 0        // 6000
#define WS_H0    12000    // 100
#define WS_GI    12160    // 18000 (60 x 300)
#define WS_H     30160    // 6000  (60 x 100)
#define WS_LT    36400    // 60 target-token logits
#define WS_FLAGH 36600    // unsigned flag: H ready
#define WS_FLAGD 36632    // unsigned counter: logits blocks done
#define WS_MS    36864    // float2[60][MSSTRIDE]
#define WS_WBF   1048576  // float offset 4 MiB: ushort[100000][128] bf16 w_out

typedef __attribute__((ext_vector_type(8))) short short8;
typedef __attribute__((ext_vector_type(4))) float f32x4;

static __device__ __forceinline__ unsigned short f2bf(float f) {
    union { float f; unsigned u; } x; x.f = f;
    unsigned r = (x.u + 0x7FFFu + ((x.u >> 16) & 1u)) >> 16;
    return (unsigned short)r;
}

// ---------------- K1: facts encoder ----------------
__global__ __launch_bounds__(128) void k1_facts(const int* __restrict__ context,
                                                const float* __restrict__ emb_ctx,
                                                float* __restrict__ ws) {
    int b = blockIdx.x, tid = threadIdx.x;
    __shared__ int toks[20];
    if (tid < 20) toks[tid] = context[b * 20 + tid];
    __syncthreads();
    if (tid < 100) {
        float ef = tid * (1.f / 99.f);
        float acc = 0.f;
        #pragma unroll
        for (int s = 0; s < 20; s++) {
            float sf = s * (1.f / 19.f);
            float l = 1.f - sf - ef * (1.f - 2.f * sf);
            acc = fmaf(emb_ctx[toks[s] * 100 + tid], l, acc);
        }
        ws[WS_FACTS + b * 100 + tid] = acc;
    }
}

// ---------------- K2: h0 (blocks 0..99) + gi_all (blocks 100..159) ----------------
__global__ __launch_bounds__(320) void k2_h0_gi(const float* __restrict__ w1,
                                                const float* __restrict__ b1,
                                                const float* __restrict__ w_ih,
                                                const float* __restrict__ b_ih,
                                                const int* __restrict__ desc,
                                                const float* __restrict__ emb_dec,
                                                float* __restrict__ ws) {
    int b = blockIdx.x, tid = threadIdx.x;
    if (b < 100) {
        __shared__ float red[320];
        const float* facts = ws + WS_FACTS;
        const float* wr = w1 + b * 6000;
        float p = 0.f;
        for (int k = tid; k < 6000; k += 320) p = fmaf(facts[k], wr[k], p);
        red[tid] = p; __syncthreads();
        if (tid < 64) red[tid] += red[256 + tid];
        __syncthreads();
        for (int st = 128; st > 0; st >>= 1) {
            if (tid < st) red[tid] += red[tid + st];
            __syncthreads();
        }
        if (tid == 0) ws[WS_H0 + b] = red[0] + b1[b];
    } else {
        int t = b - 100;
        __shared__ float xs[100];
        __shared__ int tok_s;
        if (tid == 0) tok_s = (t == 0) ? 1 : desc[t - 1];
        __syncthreads();
        if (tid < 100) xs[tid] = emb_dec[tok_s * 100 + tid];
        __syncthreads();
        if (tid < 300) {
            float p = b_ih[tid];
            const float* wr = w_ih + tid * 100;
            #pragma unroll 4
            for (int k = 0; k < 100; k++) p = fmaf(wr[k], xs[k], p);
            ws[WS_GI + t * 300 + tid] = p;
        }
    }
}

// ---------------- K3 (mega-fused): GRU + cvt + logits + finalize ----------------
// Block 0: GRU (r5 structure, unchanged) -> logit_tok from LDS H -> H dump ->
//          fence + flag release (atomicExch -> 1; poisoned initial 0xAAAAAAAA != 1).
// Blocks 1..255: convert w_out->bf16 (runs under GRU's shadow), spin on flag
//          (s_sleep backoff; all 256 blocks co-resident on 256 CUs -> no
//          deadlock), then logits (1275 waves, online softmax partials), then
//          counting atomic (base = poison 0xAAAAAAAA) elects the LAST block to
//          combine partials and write the final loss to out[0].
__global__ __launch_bounds__(320, 1) void k3_mega(const float* __restrict__ w_hh,
                                                  const float* __restrict__ b_hh,
                                                  const float* __restrict__ w_out,
                                                  const float* __restrict__ b_out,
                                                  const int* __restrict__ desc,
                                                  float* __restrict__ ws,
                                                  float* __restrict__ out) {
    __shared__ __align__(16) float gi_lds[18000];
    __shared__ __align__(16) float h_hist[6000];
    __shared__ __align__(16) unsigned short h_bf[128];
    __shared__ float loss_t[64];
    __shared__ unsigned lds_last;

    const int tid = threadIdx.x;
    const int wave = tid >> 6, lane = tid & 63;
    const int q = lane >> 4, n = lane & 15;
    unsigned* flagH = (unsigned*)(ws + WS_FLAGH);
    unsigned* flagD = (unsigned*)(ws + WS_FLAGD);

    if (blockIdx.x != 0) {
        // ======== worker path ========
        const int bid = blockIdx.x - 1;
        unsigned short* wbf = (unsigned short*)(ws + WS_WBF);
        // ---- phase 1: w_out fp32 -> bf16 (K padded to 128) ----
        {
            uint2* out4 = (uint2*)wbf;
            const int total = VOCAB * 128 / 4;
            const int stride = 255 * 320;
            for (int i = bid * 320 + tid; i < total; i += stride) {
                int row = i >> 5;
                int k0 = (i & 31) * 4;
                uint2 r;
                if (k0 + 4 <= 100) {
                    float4 v = *(const float4*)(w_out + row * 100 + k0);
                    r.x = (unsigned)f2bf(v.x) | ((unsigned)f2bf(v.y) << 16);
                    r.y = (unsigned)f2bf(v.z) | ((unsigned)f2bf(v.w) << 16);
                } else { r.x = 0u; r.y = 0u; }
                out4[i] = r;
            }
        }
        // ---- phase 2: wait for H ----
        if (tid == 0) {
            unsigned v;
            do {
                v = atomicAdd(flagH, 0u);
                if (v != 1u) __builtin_amdgcn_s_sleep(16);
            } while (v != 1u);
        }
        __syncthreads();
        __threadfence();

        // ---- phase 3: logits + online softmax ----
        const float* H = ws + WS_H;
        float* ms = ws + WS_MS;
        const int gw = bid * 5 + wave;
        const int k_base = q * 8;

        short8 afr[4][4];
        #pragma unroll
        for (int mt = 0; mt < 4; mt++) {
            int m = mt * 16 + n;
            #pragma unroll
            for (int kt = 0; kt < 4; kt++) {
                int k0 = kt * 32 + k_base;
                float va[8];
                #pragma unroll
                for (int jj = 0; jj < 8; jj++) va[jj] = 0.f;
                if (m < 60) {
                    if (k0 + 4 <= 100) {
                        float4 a = *(const float4*)(H + m * 100 + k0);
                        va[0] = a.x; va[1] = a.y; va[2] = a.z; va[3] = a.w;
                    }
                    if (k0 + 8 <= 100) {
                        float4 b = *(const float4*)(H + m * 100 + k0 + 4);
                        va[4] = b.x; va[5] = b.y; va[6] = b.z; va[7] = b.w;
                    }
                }
                short8 f;
                #pragma unroll
                for (int jj = 0; jj < 8; jj++) f[jj] = (short)f2bf(va[jj]);
                afr[mt][kt] = f;
            }
        }

        float mS[16], sS[16];
        #pragma unroll
        for (int i = 0; i < 16; i++) { mS[i] = -3.0e38f; sS[i] = 0.f; }

        for (int c = gw; c < NCHUNK; c += NWLOG) {
            int row = c * 16 + n;
            const short8* bp = (const short8*)(wbf + (size_t)row * 128);
            short8 bfr[4];
            #pragma unroll
            for (int kt = 0; kt < 4; kt++) bfr[kt] = bp[kt * 4 + q];
            float bo = b_out[row];
            #pragma unroll
            for (int mt = 0; mt < 4; mt++) {
                f32x4 acc = {0.f, 0.f, 0.f, 0.f};
                acc = __builtin_amdgcn_mfma_f32_16x16x32_bf16(afr[mt][0], bfr[0], acc, 0, 0, 0);
                acc = __builtin_amdgcn_mfma_f32_16x16x32_bf16(afr[mt][1], bfr[1], acc, 0, 0, 0);
                acc = __builtin_amdgcn_mfma_f32_16x16x32_bf16(afr[mt][2], bfr[2], acc, 0, 0, 0);
                acc = __builtin_amdgcn_mfma_f32_16x16x32_bf16(afr[mt][3], bfr[3], acc, 0, 0, 0);
                #pragma unroll
                for (int reg = 0; reg < 4; reg++) {
                    float x = acc[reg] + bo;
                    int i = mt * 4 + reg;
                    float mo = mS[i];
                    float mn = fmaxf(mo, x);
                    sS[i] = sS[i] * __expf(mo - mn) + __expf(x - mn);
                    mS[i] = mn;
                }
            }
        }

        #pragma unroll
        for (int i = 0; i < 16; i++) {
            float m = mS[i], s = sS[i];
            #pragma unroll
            for (int off = 1; off < 16; off <<= 1) {
                float m2 = __shfl_xor(m, off);
                float s2 = __shfl_xor(s, off);
                float mn = fmaxf(m, m2);
                s = s * __expf(m - mn) + s2 * __expf(m2 - mn);
                m = mn;
            }
            mS[i] = m; sS[i] = s;
        }
        if (n == 0) {
            #pragma unroll
            for (int mt = 0; mt < 4; mt++) {
                #pragma unroll
                for (int reg = 0; reg < 4; reg++) {
                    int t = mt * 16 + q * 4 + reg;
                    if (t < 60) {
                        int i = mt * 4 + reg;
                        float2 val; val.x = mS[i]; val.y = sS[i];
                        ((float2*)ms)[t * MSSTRIDE + gw] = val;
                    }
                }
            }
        }

        // ---- phase 4: last block finalizes ----
        __threadfence();
        __syncthreads();
        if (tid == 0) {
            unsigned old = atomicAdd(flagD, 1u);
            lds_last = (old == 0xAAAAAAAAu + 254u) ? 1u : 0u;
        }
        __syncthreads();
        if (lds_last) {
            __threadfence();
            const float2* msp = (const float2*)(ws + WS_MS);
            for (int tt = 0; tt < 12; tt++) {
                int t = wave * 12 + tt;
                float m = -3.0e38f, s = 0.f;
                for (int i = lane; i < NWLOG; i += 64) {
                    float2 p = msp[t * MSSTRIDE + i];
                    float mn = fmaxf(m, p.x);
                    s = s * __expf(m - mn) + p.y * __expf(p.x - mn);
                    m = mn;
                }
                #pragma unroll
                for (int off = 1; off < 64; off <<= 1) {
                    float m2 = __shfl_xor(m, off);
                    float s2 = __shfl_xor(s, off);
                    float mn = fmaxf(m, m2);
                    s = s * __expf(m - mn) + s2 * __expf(m2 - mn);
                    m = mn;
                }
                if (lane == 0) loss_t[t] = m + logf(s) - ws[WS_LT + t];
            }
            __syncthreads();
            if (tid == 0) {
                float tot = 0.f;
                for (int t = 0; t < 60; t++) tot += loss_t[t];
                out[0] = tot;
            }
        }
        return;
    }

    // ======== block 0: GRU ========
    const int l = lane;
    const int j = 20 * wave + l;          // gate index, valid iff l < 20

    short8 bfr[16];
    #pragma unroll
    for (int i = 0; i < 4; i++) {
        int row;
        if (i == 0)      row = 20 * wave + n;
        else if (i == 1) row = 100 + 20 * wave + n;
        else if (i == 2) row = 200 + 20 * wave + n;
        else {
            if (n < 4)       row = 20 * wave + 16 + n;
            else if (n < 8)  row = 100 + 20 * wave + 12 + n;
            else if (n < 12) row = 200 + 20 * wave + 8 + n;
            else             row = -1;
        }
        const float* wr = w_hh + (row < 0 ? 0 : row) * 100;
        #pragma unroll
        for (int kt = 0; kt < 4; kt++) {
            int k0 = kt * 32 + q * 8;
            float va[8];
            #pragma unroll
            for (int jj = 0; jj < 8; jj++) va[jj] = 0.f;
            if (row >= 0) {
                if (k0 + 4 <= 100) {
                    float4 a = *(const float4*)(wr + k0);
                    va[0] = a.x; va[1] = a.y; va[2] = a.z; va[3] = a.w;
                }
                if (k0 + 8 <= 100) {
                    float4 b = *(const float4*)(wr + k0 + 4);
                    va[4] = b.x; va[5] = b.y; va[6] = b.z; va[7] = b.w;
                }
            }
            short8 f;
            #pragma unroll
            for (int jj = 0; jj < 8; jj++) f[jj] = (short)f2bf(va[jj]);
            bfr[i * 4 + kt] = f;
        }
    }

    {
        const float4* g4 = (const float4*)(ws + WS_GI);
        float4* l4 = (float4*)gi_lds;
        for (int k = tid; k < 4500; k += 320) l4[k] = g4[k];
    }

    float hreg = 0.f, bh0 = 0.f, bh1 = 0.f, bh2 = 0.f;
    if (l < 20) {
        hreg = ws[WS_H0 + j];
        bh0 = b_hh[j]; bh1 = b_hh[100 + j]; bh2 = b_hh[200 + j];
        h_bf[j] = f2bf(hreg);
    }
    if (tid >= 100 && tid < 128) h_bf[tid] = 0;
    __syncthreads();

    const int s_lo  = (l < 16) ? l : 0;
    const int s3r   = (l < 16) ? 0 : (l - 16);
    const int s3z   = (l < 16) ? 4 : (l - 12);
    const int s3n   = (l < 16) ? 8 : (l - 8);

    for (int t = 0; t < 60; t++) {
        short8 afr[4];
        #pragma unroll
        for (int kt = 0; kt < 4; kt++)
            afr[kt] = *(const short8*)&h_bf[kt * 32 + q * 8];

        float val[4];
        #pragma unroll
        for (int i = 0; i < 4; i++) {
            f32x4 z4 = {0.f, 0.f, 0.f, 0.f};
            f32x4 a01 = __builtin_amdgcn_mfma_f32_16x16x32_bf16(afr[0], bfr[i * 4 + 0], z4, 0, 0, 0);
            a01 = __builtin_amdgcn_mfma_f32_16x16x32_bf16(afr[1], bfr[i * 4 + 1], a01, 0, 0, 0);
            f32x4 a23 = __builtin_amdgcn_mfma_f32_16x16x32_bf16(afr[2], bfr[i * 4 + 2], z4, 0, 0, 0);
            a23 = __builtin_amdgcn_mfma_f32_16x16x32_bf16(afr[3], bfr[i * 4 + 3], a23, 0, 0, 0);
            val[i] = a01[0] + a23[0];
        }

        float v0  = __shfl(val[0], s_lo, 64);
        float v1  = __shfl(val[1], s_lo, 64);
        float v2  = __shfl(val[2], s_lo, 64);
        float w3r = __shfl(val[3], s3r, 64);
        float w3z = __shfl(val[3], s3z, 64);
        float w3n = __shfl(val[3], s3n, 64);

        if (l < 20) {
            float ghr = ((l < 16) ? v0 : w3r) + bh0;
            float ghz = ((l < 16) ? v1 : w3z) + bh1;
            float ghn = ((l < 16) ? v2 : w3n) + bh2;
            float gir = gi_lds[t * 300 + j];
            float giz = gi_lds[t * 300 + 100 + j];
            float gin = gi_lds[t * 300 + 200 + j];
            float r = 1.f / (1.f + __expf(-(gir + ghr)));
            float z = 1.f / (1.f + __expf(-(giz + ghz)));
            float a = fmaf(r, ghn, gin);
            float tt = __expf(-2.f * fabsf(a));
            float nn = copysignf((1.f - tt) / (1.f + tt), a);
            hreg = (1.f - z) * nn + z * hreg;
            h_bf[j] = f2bf(hreg);
            h_hist[t * 100 + j] = hreg;
        }
        __syncthreads();
    }

    // dump H to global
    {
        float4* Hg = (float4*)(ws + WS_H);
        const float4* h4 = (const float4*)h_hist;
        for (int k = tid; k < 1500; k += 320) Hg[k] = h4[k];
    }

    // target-token logits from LDS-resident H (absorbs old k5 dot)
    for (int tt = 0; tt < 12; tt++) {
        int t = wave * 12 + tt;
        int tok = desc[t];
        const float* wr = w_out + (size_t)tok * 100;
        float p = 0.f;
        if (l < 50) {
            p = h_hist[t * 100 + 2 * l] * wr[2 * l]
              + h_hist[t * 100 + 2 * l + 1] * wr[2 * l + 1];
        }
        #pragma unroll
        for (int off = 1; off < 64; off <<= 1) p += __shfl_xor(p, off);
        if (l == 0) ws[WS_LT + t] = p + b_out[tok];
    }

    // release H
    __threadfence();
    __syncthreads();
    if (tid == 0) atomicExch(flagH, 1u);
}

extern "C" void kernel_launch(void* const* d_in, const int* in_sizes, int n_in,
                              void* d_out, int out_size, void* d_ws, size_t ws_size,
                              hipStream_t stream) {
    const int*   context = (const int*)d_in[0];
    // d_in[1] = fact_lengths (unused by reference)
    const int*   desc    = (const int*)d_in[2];
    const float* emb_ctx = (const float*)d_in[3];
    const float* emb_dec = (const float*)d_in[4];
    const float* w1      = (const float*)d_in[5];
    const float* b1      = (const float*)d_in[6];
    const float* w_ih    = (const float*)d_in[7];
    const float* w_hh    = (const float*)d_in[8];
    const float* b_ih    = (const float*)d_in[9];
    const float* b_hh    = (const float*)d_in[10];
    const float* w_out   = (const float*)d_in[11];
    const float* b_out   = (const float*)d_in[12];
    float* out = (float*)d_out;
    float* ws  = (float*)d_ws;

    k1_facts<<<60,  128, 0, stream>>>(context, emb_ctx, ws);
    k2_h0_gi<<<160, 320, 0, stream>>>(w1, b1, w_ih, b_ih, desc, emb_dec, ws);
    k3_mega <<<256, 320, 0, stream>>>(w_hh, b_hh, w_out, b_out, desc, ws, out);
}

// Round 7
// 245.500 us; speedup vs baseline: 1.3990x; 1.3990x over previous
//
#include <hip/hip_runtime.h>
#include <hip/hip_bf16.h>
#include <math.h>

#define VOCAB 100000
#define EMB 100
#define HID 100
#define CTX_LEN 60
#define FACT_LEN 20
#define DESC_LEN 60
#define NCHUNK (VOCAB / 16)   // 6250 column chunks of 16
#define NWAVES 1024

// workspace layout (float offsets)
#define WS_H0    12000    // 100
#define WS_GI    12160    // 18000 (60 x 300)
#define WS_H     30160    // 6000  (60 x 100)
#define WS_MS    36864    // float2[60][NWAVES]

typedef __attribute__((ext_vector_type(8))) short short8;
typedef __attribute__((ext_vector_type(4))) float f32x4;

static __device__ __forceinline__ unsigned short f2bf(float f) {
    union { float f; unsigned u; } x; x.f = f;
    unsigned r = (x.u + 0x7FFFu + ((x.u >> 16) & 1u)) >> 16;
    return (unsigned short)r;
}

// ---------------- K1: fused prep ----------------
// blocks 0..99 : h0[b] directly from embeddings (no facts materialization):
//                h0[b] = sum_{c,s} ( sum_e emb_ctx[ctx[c,s]][e] * l(s,e) * w1[b][c*100+e] )
// blocks 100..159: gi[t] = W_ih @ emb_dec[x_t] + b_ih   (teacher forcing)
__global__ __launch_bounds__(320) void k1_prep(const int* __restrict__ context,
                                               const int* __restrict__ desc,
                                               const float* __restrict__ emb_ctx,
                                               const float* __restrict__ emb_dec,
                                               const float* __restrict__ w1,
                                               const float* __restrict__ b1,
                                               const float* __restrict__ w_ih,
                                               const float* __restrict__ b_ih,
                                               float* __restrict__ ws,
                                               float* __restrict__ out) {
    int b = blockIdx.x, tid = threadIdx.x;
    if (b < 100) {
        __shared__ int toks[1200];
        __shared__ float red[320];
        for (int i = tid; i < 1200; i += 320) toks[i] = context[i];
        __syncthreads();
        const float* wr = w1 + b * 6000;
        float acc = 0.f;
        // 1200 (c,s) pairs strided over 320 threads; 100 MACs each
        for (int p = tid; p < 1200; p += 320) {
            int c = p / 20, s = p - c * 20;
            const float* er = emb_ctx + (size_t)toks[p] * 100;
            const float* wc = wr + c * 100;
            float sf = s * (1.f / 19.f);
            float l0 = 1.f - sf;              // l = l0 - ef*l1
            float l1 = 1.f - 2.f * sf;
            float pacc = 0.f;
            #pragma unroll 4
            for (int e = 0; e < 100; e++) {
                float l = fmaf(-(e * (1.f / 99.f)), l1, l0);
                pacc = fmaf(er[e] * l, wc[e], pacc);
            }
            acc += pacc;
        }
        red[tid] = acc; __syncthreads();
        if (tid < 64) red[tid] += red[256 + tid];
        __syncthreads();
        for (int st = 128; st > 0; st >>= 1) {
            if (tid < st) red[tid] += red[tid + st];
            __syncthreads();
        }
        if (tid == 0) {
            ws[WS_H0 + b] = red[0] + b1[b];
            if (b == 0) out[0] = 0.f;   // d_out poisoned; k5 atomicAdds into it
        }
    } else {
        int t = b - 100;
        __shared__ float xs[100];
        __shared__ int tok_s;
        if (tid == 0) tok_s = (t == 0) ? 1 : desc[t - 1];
        __syncthreads();
        if (tid < 100) xs[tid] = emb_dec[tok_s * 100 + tid];
        __syncthreads();
        if (tid < 300) {
            float p = b_ih[tid];
            const float* wr = w_ih + tid * 100;
            #pragma unroll 4
            for (int k = 0; k < 100; k++) p = fmaf(wr[k], xs[k], p);
            ws[WS_GI + t * 300 + tid] = p;
        }
    }
}

// ---------------- K3: sequential GRU via MFMA (r4 structure — best known) ----------------
// 41us across three structural variants -> step-latency-bound; keep known-good.
__global__ __launch_bounds__(320, 1) void k3_gru(const float* __restrict__ w_hh,
                                                 const float* __restrict__ b_hh,
                                                 float* __restrict__ ws) {
    __shared__ __align__(16) float gi_lds[18000];
    __shared__ __align__(16) float h_hist[6000];
    __shared__ __align__(16) unsigned short h_bf[128];

    const int tid = threadIdx.x;
    const int wave = tid >> 6, lane = tid & 63;
    const int q = lane >> 4, n = lane & 15;
    const int l = lane;
    const int j = 20 * wave + l;          // gate index, valid iff l < 20

    // B-fragments with permuted rows (wave-local gh coverage)
    short8 bfr[16];
    #pragma unroll
    for (int i = 0; i < 4; i++) {
        int row;
        if (i == 0)      row = 20 * wave + n;
        else if (i == 1) row = 100 + 20 * wave + n;
        else if (i == 2) row = 200 + 20 * wave + n;
        else {
            if (n < 4)       row = 20 * wave + 16 + n;
            else if (n < 8)  row = 100 + 20 * wave + 12 + n;
            else if (n < 12) row = 200 + 20 * wave + 8 + n;
            else             row = -1;
        }
        const float* wr = w_hh + (row < 0 ? 0 : row) * 100;
        #pragma unroll
        for (int kt = 0; kt < 4; kt++) {
            int k0 = kt * 32 + q * 8;
            float va[8];
            #pragma unroll
            for (int jj = 0; jj < 8; jj++) va[jj] = 0.f;
            if (row >= 0) {
                if (k0 + 4 <= 100) {
                    float4 a = *(const float4*)(wr + k0);
                    va[0] = a.x; va[1] = a.y; va[2] = a.z; va[3] = a.w;
                }
                if (k0 + 8 <= 100) {
                    float4 b = *(const float4*)(wr + k0 + 4);
                    va[4] = b.x; va[5] = b.y; va[6] = b.z; va[7] = b.w;
                }
            }
            short8 f;
            #pragma unroll
            for (int jj = 0; jj < 8; jj++) f[jj] = (short)f2bf(va[jj]);
            bfr[i * 4 + kt] = f;
        }
    }

    {
        const float4* g4 = (const float4*)(ws + WS_GI);
        float4* l4 = (float4*)gi_lds;
        for (int k = tid; k < 4500; k += 320) l4[k] = g4[k];
    }

    float hreg = 0.f, bh0 = 0.f, bh1 = 0.f, bh2 = 0.f;
    if (l < 20) {
        hreg = ws[WS_H0 + j];
        bh0 = b_hh[j]; bh1 = b_hh[100 + j]; bh2 = b_hh[200 + j];
        h_bf[j] = f2bf(hreg);
    }
    if (tid >= 100 && tid < 128) h_bf[tid] = 0;
    __syncthreads();

    const int s_lo  = (l < 16) ? l : 0;
    const int s3r   = (l < 16) ? 0 : (l - 16);
    const int s3z   = (l < 16) ? 4 : (l - 12);
    const int s3n   = (l < 16) ? 8 : (l - 8);

    for (int t = 0; t < 60; t++) {
        short8 afr[4];
        #pragma unroll
        for (int kt = 0; kt < 4; kt++)
            afr[kt] = *(const short8*)&h_bf[kt * 32 + q * 8];

        float val[4];
        #pragma unroll
        for (int i = 0; i < 4; i++) {
            f32x4 z4 = {0.f, 0.f, 0.f, 0.f};
            f32x4 a01 = __builtin_amdgcn_mfma_f32_16x16x32_bf16(afr[0], bfr[i * 4 + 0], z4, 0, 0, 0);
            a01 = __builtin_amdgcn_mfma_f32_16x16x32_bf16(afr[1], bfr[i * 4 + 1], a01, 0, 0, 0);
            f32x4 a23 = __builtin_amdgcn_mfma_f32_16x16x32_bf16(afr[2], bfr[i * 4 + 2], z4, 0, 0, 0);
            a23 = __builtin_amdgcn_mfma_f32_16x16x32_bf16(afr[3], bfr[i * 4 + 3], a23, 0, 0, 0);
            val[i] = a01[0] + a23[0];
        }

        float v0  = __shfl(val[0], s_lo, 64);
        float v1  = __shfl(val[1], s_lo, 64);
        float v2  = __shfl(val[2], s_lo, 64);
        float w3r = __shfl(val[3], s3r, 64);
        float w3z = __shfl(val[3], s3z, 64);
        float w3n = __shfl(val[3], s3n, 64);

        if (l < 20) {
            float ghr = ((l < 16) ? v0 : w3r) + bh0;
            float ghz = ((l < 16) ? v1 : w3z) + bh1;
            float ghn = ((l < 16) ? v2 : w3n) + bh2;
            float gir = gi_lds[t * 300 + j];
            float giz = gi_lds[t * 300 + 100 + j];
            float gin = gi_lds[t * 300 + 200 + j];
            float r = 1.f / (1.f + __expf(-(gir + ghr)));
            float z = 1.f / (1.f + __expf(-(giz + ghz)));
            float a = fmaf(r, ghn, gin);
            float tt = __expf(-2.f * fabsf(a));
            float nn = copysignf((1.f - tt) / (1.f + tt), a);
            hreg = (1.f - z) * nn + z * hreg;
            h_bf[j] = f2bf(hreg);
            h_hist[t * 100 + j] = hreg;
        }
        __syncthreads();
    }

    {
        float4* Hg = (float4*)(ws + WS_H);
        const float4* h4 = (const float4*)h_hist;
        for (int k = tid; k < 1500; k += 320) Hg[k] = h4[k];
    }
}

// ---------------- K4: logits GEMM (bf16 MFMA, fp32 w_out loads) + online softmax ----------------
__global__ __launch_bounds__(256, 1) void k4_logits(const float* __restrict__ w_out,
                                                    const float* __restrict__ b_out,
                                                    float* __restrict__ ws) {
    const float* H = ws + WS_H;
    float* ms = ws + WS_MS;
    const int lane = threadIdx.x & 63;
    const int gw = blockIdx.x * 4 + (threadIdx.x >> 6);
    const int q = lane >> 4, n = lane & 15;
    const int k_base = q * 8;

    short8 afr[4][4];
    #pragma unroll
    for (int mt = 0; mt < 4; mt++) {
        int m = mt * 16 + n;
        #pragma unroll
        for (int kt = 0; kt < 4; kt++) {
            int k0 = kt * 32 + k_base;
            float va[8];
            #pragma unroll
            for (int jj = 0; jj < 8; jj++) va[jj] = 0.f;
            if (m < 60) {
                if (k0 + 4 <= 100) {
                    float4 a = *(const float4*)(H + m * 100 + k0);
                    va[0] = a.x; va[1] = a.y; va[2] = a.z; va[3] = a.w;
                }
                if (k0 + 8 <= 100) {
                    float4 b = *(const float4*)(H + m * 100 + k0 + 4);
                    va[4] = b.x; va[5] = b.y; va[6] = b.z; va[7] = b.w;
                }
            }
            short8 f;
            #pragma unroll
            for (int jj = 0; jj < 8; jj++) f[jj] = (short)f2bf(va[jj]);
            afr[mt][kt] = f;
        }
    }

    float mS[16], sS[16];
    #pragma unroll
    for (int i = 0; i < 16; i++) { mS[i] = -3.0e38f; sS[i] = 0.f; }

    for (int c = gw; c < NCHUNK; c += NWAVES) {
        int row = c * 16 + n;
        short8 bfr[4];
        #pragma unroll
        for (int kt = 0; kt < 4; kt++) {
            int k0 = kt * 32 + k_base;
            float va[8];
            #pragma unroll
            for (int jj = 0; jj < 8; jj++) va[jj] = 0.f;
            if (k0 + 4 <= 100) {
                float4 a = *(const float4*)(w_out + row * 100 + k0);
                va[0] = a.x; va[1] = a.y; va[2] = a.z; va[3] = a.w;
            }
            if (k0 + 8 <= 100) {
                float4 b = *(const float4*)(w_out + row * 100 + k0 + 4);
                va[4] = b.x; va[5] = b.y; va[6] = b.z; va[7] = b.w;
            }
            short8 f;
            #pragma unroll
            for (int jj = 0; jj < 8; jj++) f[jj] = (short)f2bf(va[jj]);
            bfr[kt] = f;
        }
        float bo = b_out[row];
        #pragma unroll
        for (int mt = 0; mt < 4; mt++) {
            f32x4 acc = {0.f, 0.f, 0.f, 0.f};
            acc = __builtin_amdgcn_mfma_f32_16x16x32_bf16(afr[mt][0], bfr[0], acc, 0, 0, 0);
            acc = __builtin_amdgcn_mfma_f32_16x16x32_bf16(afr[mt][1], bfr[1], acc, 0, 0, 0);
            acc = __builtin_amdgcn_mfma_f32_16x16x32_bf16(afr[mt][2], bfr[2], acc, 0, 0, 0);
            acc = __builtin_amdgcn_mfma_f32_16x16x32_bf16(afr[mt][3], bfr[3], acc, 0, 0, 0);
            #pragma unroll
            for (int reg = 0; reg < 4; reg++) {
                float x = acc[reg] + bo;
                int i = mt * 4 + reg;
                float mo = mS[i];
                float mn = fmaxf(mo, x);
                sS[i] = sS[i] * __expf(mo - mn) + __expf(x - mn);
                mS[i] = mn;
            }
        }
    }

    #pragma unroll
    for (int i = 0; i < 16; i++) {
        float m = mS[i], s = sS[i];
        #pragma unroll
        for (int off = 1; off < 16; off <<= 1) {
            float m2 = __shfl_xor(m, off);
            float s2 = __shfl_xor(s, off);
            float mn = fmaxf(m, m2);
            s = s * __expf(m - mn) + s2 * __expf(m2 - mn);
            m = mn;
        }
        mS[i] = m; sS[i] = s;
    }
    if (n == 0) {
        #pragma unroll
        for (int mt = 0; mt < 4; mt++) {
            #pragma unroll
            for (int reg = 0; reg < 4; reg++) {
                int t = mt * 16 + q * 4 + reg;
                if (t < 60) {
                    int i = mt * 4 + reg;
                    float2 val; val.x = mS[i]; val.y = sS[i];
                    ((float2*)ms)[t * NWAVES + gw] = val;
                }
            }
        }
    }
}

// ---------------- K5: combine partials per t, add -logit[tok], accumulate loss ----------------
__global__ __launch_bounds__(256) void k5_final(const int* __restrict__ desc,
                                                const float* __restrict__ w_out,
                                                const float* __restrict__ b_out,
                                                const float* __restrict__ ws,
                                                float* __restrict__ out) {
    int t = blockIdx.x, tid = threadIdx.x;
    __shared__ float sm[256], ss[256], sd[256];
    const float2* ms = (const float2*)(ws + WS_MS);
    float m = -3.0e38f, s = 0.f;
    for (int i = tid; i < NWAVES; i += 256) {
        float2 p = ms[t * NWAVES + i];
        float mn = fmaxf(m, p.x);
        s = s * __expf(m - mn) + p.y * __expf(p.x - mn);
        m = mn;
    }
    sm[tid] = m; ss[tid] = s; __syncthreads();
    for (int st = 128; st > 0; st >>= 1) {
        if (tid < st) {
            float mo = sm[tid], so = ss[tid];
            float m2 = sm[tid + st], s2 = ss[tid + st];
            float mn = fmaxf(mo, m2);
            sm[tid] = mn;
            ss[tid] = so * __expf(mo - mn) + s2 * __expf(m2 - mn);
        }
        __syncthreads();
    }
    int tok = desc[t];
    float p = 0.f;
    if (tid < 100) p = ws[WS_H + t * 100 + tid] * w_out[tok * 100 + tid];
    sd[tid] = p; __syncthreads();
    for (int st = 128; st > 0; st >>= 1) {
        if (tid < st) sd[tid] += sd[tid + st];
        __syncthreads();
    }
    if (tid == 0) {
        float logit = sd[0] + b_out[tok];
        float loss = sm[0] + logf(ss[0]) - logit;
        atomicAdd(out, loss);
    }
}

extern "C" void kernel_launch(void* const* d_in, const int* in_sizes, int n_in,
                              void* d_out, int out_size, void* d_ws, size_t ws_size,
                              hipStream_t stream) {
    const int*   context = (const int*)d_in[0];
    // d_in[1] = fact_lengths (unused by reference)
    const int*   desc    = (const int*)d_in[2];
    const float* emb_ctx = (const float*)d_in[3];
    const float* emb_dec = (const float*)d_in[4];
    const float* w1      = (const float*)d_in[5];
    const float* b1      = (const float*)d_in[6];
    const float* w_ih    = (const float*)d_in[7];
    const float* w_hh    = (const float*)d_in[8];
    const float* b_ih    = (const float*)d_in[9];
    const float* b_hh    = (const float*)d_in[10];
    const float* w_out   = (const float*)d_in[11];
    const float* b_out   = (const float*)d_in[12];
    float* out = (float*)d_out;
    float* ws  = (float*)d_ws;

    k1_prep  <<<160, 320, 0, stream>>>(context, desc, emb_ctx, emb_dec,
                                       w1, b1, w_ih, b_ih, ws, out);
    k3_gru   <<<1,   320, 0, stream>>>(w_hh, b_hh, ws);
    k4_logits<<<256, 256, 0, stream>>>(w_out, b_out, ws);
    k5_final <<<60,  256, 0, stream>>>(desc, w_out, b_out, ws, out);
}

// Round 8
// 204.702 us; speedup vs baseline: 1.6779x; 1.1993x over previous
//
#include <hip/hip_runtime.h>
#include <hip/hip_bf16.h>
#include <math.h>

#define VOCAB 100000
#define EMB 100
#define HID 100
#define CTX_LEN 60
#define FACT_LEN 20
#define DESC_LEN 60
#define NCHUNK (VOCAB / 16)   // 6250 column chunks of 16
#define NWAVES 1024

// workspace layout (float offsets)
#define WS_FACTS 0        // 6000
#define WS_X     6000     // 6000
#define WS_H0    12000    // 128
#define WS_GI    12160    // 18000 (60 x 300)
#define WS_H     30160    // 6000  (60 x 100)
#define WS_MS    36864    // float2[60][NWAVES]

typedef __attribute__((ext_vector_type(8))) short short8;
typedef __attribute__((ext_vector_type(4))) float f32x4;

static __device__ __forceinline__ unsigned short f2bf(float f) {
    union { float f; unsigned u; } x; x.f = f;
    unsigned r = (x.u + 0x7FFFu + ((x.u >> 16) & 1u)) >> 16;
    return (unsigned short)r;
}

// ---------------- K1: facts encoder + decoder input embeddings + zero d_out ----------------
__global__ __launch_bounds__(128) void k1_prep(const int* __restrict__ context,
                                               const int* __restrict__ desc,
                                               const float* __restrict__ emb_ctx,
                                               const float* __restrict__ emb_dec,
                                               float* __restrict__ ws,
                                               float* __restrict__ out) {
    int b = blockIdx.x, tid = threadIdx.x;
    if (b < 60) {
        __shared__ int toks[20];
        if (tid < 20) toks[tid] = context[b * 20 + tid];
        __syncthreads();
        if (tid < 100) {
            float ef = tid * (1.f / 99.f);
            float acc = 0.f;
            #pragma unroll
            for (int s = 0; s < 20; s++) {
                float sf = s * (1.f / 19.f);
                float l = 1.f - sf - ef * (1.f - 2.f * sf);
                acc = fmaf(emb_ctx[toks[s] * 100 + tid], l, acc);
            }
            ws[WS_FACTS + b * 100 + tid] = acc;
        }
    } else {
        int t = b - 60;
        int tok = (t == 0) ? 1 : desc[t - 1];
        if (tid < 100) ws[WS_X + t * 100 + tid] = emb_dec[tok * 100 + tid];
        if (b == 60 && tid == 0) out[0] = 0.f;   // d_out is poisoned; K5 atomicAdds into it
    }
}

// ---------------- K2: h0 (blocks 0..99) + gi_all (blocks 100..159) ----------------
__global__ __launch_bounds__(320) void k2_h0_gi(const float* __restrict__ w1,
                                                const float* __restrict__ b1,
                                                const float* __restrict__ w_ih,
                                                const float* __restrict__ b_ih,
                                                float* __restrict__ ws) {
    int b = blockIdx.x, tid = threadIdx.x;
    if (b < 100) {
        __shared__ float red[320];
        const float* facts = ws + WS_FACTS;
        const float* wr = w1 + b * 6000;
        float p = 0.f;
        for (int k = tid; k < 6000; k += 320) p = fmaf(facts[k], wr[k], p);
        red[tid] = p; __syncthreads();
        if (tid < 64) red[tid] += red[256 + tid];
        __syncthreads();
        for (int st = 128; st > 0; st >>= 1) {
            if (tid < st) red[tid] += red[tid + st];
            __syncthreads();
        }
        if (tid == 0) ws[WS_H0 + b] = red[0] + b1[b];
    } else {
        int t = b - 100;
        __shared__ float xs[100];
        if (tid < 100) xs[tid] = ws[WS_X + t * 100 + tid];
        __syncthreads();
        if (tid < 300) {
            float p = b_ih[tid];
            const float* wr = w_ih + tid * 100;
            #pragma unroll 4
            for (int k = 0; k < 100; k++) p = fmaf(wr[k], xs[k], p);
            ws[WS_GI + t * 300 + tid] = p;
        }
    }
}

// ---------------- K3: sequential GRU via MFMA (r4 structure — best known, 41us) ----------------
__global__ __launch_bounds__(320, 1) void k3_gru(const float* __restrict__ w_hh,
                                                 const float* __restrict__ b_hh,
                                                 float* __restrict__ ws) {
    __shared__ __align__(16) float gi_lds[18000];
    __shared__ __align__(16) float h_hist[6000];
    __shared__ __align__(16) unsigned short h_bf[128];

    const int tid = threadIdx.x;
    const int wave = tid >> 6, lane = tid & 63;
    const int q = lane >> 4, n = lane & 15;
    const int l = lane;
    const int j = 20 * wave + l;          // gate index, valid iff l < 20

    short8 bfr[16];
    #pragma unroll
    for (int i = 0; i < 4; i++) {
        int row;
        if (i == 0)      row = 20 * wave + n;
        else if (i == 1) row = 100 + 20 * wave + n;
        else if (i == 2) row = 200 + 20 * wave + n;
        else {
            if (n < 4)       row = 20 * wave + 16 + n;
            else if (n < 8)  row = 100 + 20 * wave + 12 + n;
            else if (n < 12) row = 200 + 20 * wave + 8 + n;
            else             row = -1;
        }
        const float* wr = w_hh + (row < 0 ? 0 : row) * 100;
        #pragma unroll
        for (int kt = 0; kt < 4; kt++) {
            int k0 = kt * 32 + q * 8;
            float va[8];
            #pragma unroll
            for (int jj = 0; jj < 8; jj++) va[jj] = 0.f;
            if (row >= 0) {
                if (k0 + 4 <= 100) {
                    float4 a = *(const float4*)(wr + k0);
                    va[0] = a.x; va[1] = a.y; va[2] = a.z; va[3] = a.w;
                }
                if (k0 + 8 <= 100) {
                    float4 b = *(const float4*)(wr + k0 + 4);
                    va[4] = b.x; va[5] = b.y; va[6] = b.z; va[7] = b.w;
                }
            }
            short8 f;
            #pragma unroll
            for (int jj = 0; jj < 8; jj++) f[jj] = (short)f2bf(va[jj]);
            bfr[i * 4 + kt] = f;
        }
    }

    {
        const float4* g4 = (const float4*)(ws + WS_GI);
        float4* l4 = (float4*)gi_lds;
        for (int k = tid; k < 4500; k += 320) l4[k] = g4[k];
    }

    float hreg = 0.f, bh0 = 0.f, bh1 = 0.f, bh2 = 0.f;
    if (l < 20) {
        hreg = ws[WS_H0 + j];
        bh0 = b_hh[j]; bh1 = b_hh[100 + j]; bh2 = b_hh[200 + j];
        h_bf[j] = f2bf(hreg);
    }
    if (tid >= 100 && tid < 128) h_bf[tid] = 0;
    __syncthreads();

    const int s_lo  = (l < 16) ? l : 0;
    const int s3r   = (l < 16) ? 0 : (l - 16);
    const int s3z   = (l < 16) ? 4 : (l - 12);
    const int s3n   = (l < 16) ? 8 : (l - 8);

    for (int t = 0; t < 60; t++) {
        short8 afr[4];
        #pragma unroll
        for (int kt = 0; kt < 4; kt++)
            afr[kt] = *(const short8*)&h_bf[kt * 32 + q * 8];

        float val[4];
        #pragma unroll
        for (int i = 0; i < 4; i++) {
            f32x4 z4 = {0.f, 0.f, 0.f, 0.f};
            f32x4 a01 = __builtin_amdgcn_mfma_f32_16x16x32_bf16(afr[0], bfr[i * 4 + 0], z4, 0, 0, 0);
            a01 = __builtin_amdgcn_mfma_f32_16x16x32_bf16(afr[1], bfr[i * 4 + 1], a01, 0, 0, 0);
            f32x4 a23 = __builtin_amdgcn_mfma_f32_16x16x32_bf16(afr[2], bfr[i * 4 + 2], z4, 0, 0, 0);
            a23 = __builtin_amdgcn_mfma_f32_16x16x32_bf16(afr[3], bfr[i * 4 + 3], a23, 0, 0, 0);
            val[i] = a01[0] + a23[0];
        }

        float v0  = __shfl(val[0], s_lo, 64);
        float v1  = __shfl(val[1], s_lo, 64);
        float v2  = __shfl(val[2], s_lo, 64);
        float w3r = __shfl(val[3], s3r, 64);
        float w3z = __shfl(val[3], s3z, 64);
        float w3n = __shfl(val[3], s3n, 64);

        if (l < 20) {
            float ghr = ((l < 16) ? v0 : w3r) + bh0;
            float ghz = ((l < 16) ? v1 : w3z) + bh1;
            float ghn = ((l < 16) ? v2 : w3n) + bh2;
            float gir = gi_lds[t * 300 + j];
            float giz = gi_lds[t * 300 + 100 + j];
            float gin = gi_lds[t * 300 + 200 + j];
            float r = 1.f / (1.f + __expf(-(gir + ghr)));
            float z = 1.f / (1.f + __expf(-(giz + ghz)));
            float a = fmaf(r, ghn, gin);
            float tt = __expf(-2.f * fabsf(a));
            float nn = copysignf((1.f - tt) / (1.f + tt), a);
            hreg = (1.f - z) * nn + z * hreg;
            h_bf[j] = f2bf(hreg);
            h_hist[t * 100 + j] = hreg;
        }
        __syncthreads();
    }

    {
        float4* Hg = (float4*)(ws + WS_H);
        const float4* h4 = (const float4*)h_hist;
        for (int k = tid; k < 1500; k += 320) Hg[k] = h4[k];
    }
}

// ---------------- K4: logits GEMM + online softmax, COALESCED via wave-private LDS staging ----
// Old defect: fragment loads were 16B/lane at 400B lane stride (64 cache lines
// per wave-load, transaction-bound). Now each wave stages its 16-row chunk
// (6.4 KB CONTIGUOUS) with coalesced float4 loads, converts to bf16 on the fly,
// stores to a wave-private LDS tile (136-short row pitch: rows differ by 2 mod
// 32 banks -> conflict-free b128 fragment reads). Register-prefetch of the next
// chunk overlaps the current chunk's MFMA. No barriers (wave-local LDS).
__global__ __launch_bounds__(256, 1) void k4_logits(const float* __restrict__ w_out,
                                                    const float* __restrict__ b_out,
                                                    float* __restrict__ ws) {
    __shared__ __align__(16) unsigned short stg[4][2][16 * 136];
    const float* H = ws + WS_H;
    float* ms = ws + WS_MS;
    const int tid = threadIdx.x;
    const int wave = tid >> 6, lane = tid & 63;
    const int gw = blockIdx.x * 4 + wave;
    const int q = lane >> 4, n = lane & 15;
    const int k_base = q * 8;

    // zero the k-pad region (cols 100..135) of both wave-private buffers;
    // data rounds only ever overwrite cols 0..99, so the pad stays zero.
    for (int i = lane; i < 16 * 36; i += 64) {
        int r = i / 36, c = 100 + (i % 36);
        stg[wave][0][r * 136 + c] = 0;
        stg[wave][1][r * 136 + c] = 0;
    }

    // A fragments: H rows (t), zero-padded to 64 x 128
    short8 afr[4][4];
    #pragma unroll
    for (int mt = 0; mt < 4; mt++) {
        int m = mt * 16 + n;
        #pragma unroll
        for (int kt = 0; kt < 4; kt++) {
            int k0 = kt * 32 + k_base;
            float va[8];
            #pragma unroll
            for (int jj = 0; jj < 8; jj++) va[jj] = 0.f;
            if (m < 60) {
                if (k0 + 4 <= 100) {
                    float4 a = *(const float4*)(H + m * 100 + k0);
                    va[0] = a.x; va[1] = a.y; va[2] = a.z; va[3] = a.w;
                }
                if (k0 + 8 <= 100) {
                    float4 b = *(const float4*)(H + m * 100 + k0 + 4);
                    va[4] = b.x; va[5] = b.y; va[6] = b.z; va[7] = b.w;
                }
            }
            short8 f;
            #pragma unroll
            for (int jj = 0; jj < 8; jj++) f[jj] = (short)f2bf(va[jj]);
            afr[mt][kt] = f;
        }
    }

    float mS[16], sS[16];
    #pragma unroll
    for (int i = 0; i < 16; i++) { mS[i] = -3.0e38f; sS[i] = 0.f; }

    // chunk = 16 vocab rows = 1600 floats contiguous. 7 coalesced rounds of
    // 64 lanes x float4 (round 6: lanes 0..15 only). float4 never straddles a
    // row (100 % 4 == 0).
    float4 pf[7];
    const int f_lane = lane * 4;
    // prefetch first chunk
    {
        const float* src = w_out + (size_t)gw * 1600;
        #pragma unroll
        for (int r = 0; r < 7; r++) {
            int f = r * 256 + f_lane;
            if (f < 1600) pf[r] = *(const float4*)(src + f);
        }
    }

    int iter = 0;
    for (int c = gw; c < NCHUNK; c += NWAVES, iter++) {
        const int buf = iter & 1;
        // store staged chunk (fp32 -> bf16, wave-private tile)
        {
            unsigned short* dst = stg[wave][buf];
            #pragma unroll
            for (int r = 0; r < 7; r++) {
                int f = r * 256 + f_lane;
                if (f < 1600) {
                    int row = f / 100;
                    int col = f - row * 100;
                    uint2 v;
                    v.x = (unsigned)f2bf(pf[r].x) | ((unsigned)f2bf(pf[r].y) << 16);
                    v.y = (unsigned)f2bf(pf[r].z) | ((unsigned)f2bf(pf[r].w) << 16);
                    *(uint2*)(dst + row * 136 + col) = v;
                }
            }
        }
        // prefetch next chunk into registers
        {
            int cn = c + NWAVES;
            if (cn < NCHUNK) {
                const float* src = w_out + (size_t)cn * 1600;
                #pragma unroll
                for (int r = 0; r < 7; r++) {
                    int f = r * 256 + f_lane;
                    if (f < 1600) pf[r] = *(const float4*)(src + f);
                }
            }
        }
        // B fragments from LDS (conflict-free b128)
        const unsigned short* base = stg[wave][buf] + n * 136;
        short8 bfr[4];
        #pragma unroll
        for (int kt = 0; kt < 4; kt++)
            bfr[kt] = *(const short8*)(base + kt * 32 + k_base);
        float bo = b_out[c * 16 + n];
        #pragma unroll
        for (int mt = 0; mt < 4; mt++) {
            f32x4 acc = {0.f, 0.f, 0.f, 0.f};
            acc = __builtin_amdgcn_mfma_f32_16x16x32_bf16(afr[mt][0], bfr[0], acc, 0, 0, 0);
            acc = __builtin_amdgcn_mfma_f32_16x16x32_bf16(afr[mt][1], bfr[1], acc, 0, 0, 0);
            acc = __builtin_amdgcn_mfma_f32_16x16x32_bf16(afr[mt][2], bfr[2], acc, 0, 0, 0);
            acc = __builtin_amdgcn_mfma_f32_16x16x32_bf16(afr[mt][3], bfr[3], acc, 0, 0, 0);
            #pragma unroll
            for (int reg = 0; reg < 4; reg++) {
                float x = acc[reg] + bo;            // logit for (t = mt*16+q*4+reg, v = c*16+n)
                int i = mt * 4 + reg;
                float mo = mS[i];
                float mn = fmaxf(mo, x);
                sS[i] = sS[i] * __expf(mo - mn) + __expf(x - mn);
                mS[i] = mn;
            }
        }
    }

    // reduce (m,s) across the 16 column lanes
    #pragma unroll
    for (int i = 0; i < 16; i++) {
        float m = mS[i], s = sS[i];
        #pragma unroll
        for (int off = 1; off < 16; off <<= 1) {
            float m2 = __shfl_xor(m, off);
            float s2 = __shfl_xor(s, off);
            float mn = fmaxf(m, m2);
            s = s * __expf(m - mn) + s2 * __expf(m2 - mn);
            m = mn;
        }
        mS[i] = m; sS[i] = s;
    }
    if (n == 0) {
        #pragma unroll
        for (int mt = 0; mt < 4; mt++) {
            #pragma unroll
            for (int reg = 0; reg < 4; reg++) {
                int t = mt * 16 + q * 4 + reg;
                if (t < 60) {
                    int i = mt * 4 + reg;
                    float2 val; val.x = mS[i]; val.y = sS[i];
                    ((float2*)ms)[t * NWAVES + gw] = val;
                }
            }
        }
    }
}

// ---------------- K5: combine partials per t, add -logit[tok], accumulate loss ----------------
__global__ __launch_bounds__(256) void k5_final(const int* __restrict__ desc,
                                                const float* __restrict__ w_out,
                                                const float* __restrict__ b_out,
                                                const float* __restrict__ ws,
                                                float* __restrict__ out) {
    int t = blockIdx.x, tid = threadIdx.x;
    __shared__ float sm[256], ss[256], sd[256];
    const float2* ms = (const float2*)(ws + WS_MS);
    float m = -3.0e38f, s = 0.f;
    for (int i = tid; i < NWAVES; i += 256) {
        float2 p = ms[t * NWAVES + i];
        float mn = fmaxf(m, p.x);
        s = s * __expf(m - mn) + p.y * __expf(p.x - mn);
        m = mn;
    }
    sm[tid] = m; ss[tid] = s; __syncthreads();
    for (int st = 128; st > 0; st >>= 1) {
        if (tid < st) {
            float mo = sm[tid], so = ss[tid];
            float m2 = sm[tid + st], s2 = ss[tid + st];
            float mn = fmaxf(mo, m2);
            sm[tid] = mn;
            ss[tid] = so * __expf(mo - mn) + s2 * __expf(m2 - mn);
        }
        __syncthreads();
    }
    int tok = desc[t];
    float p = 0.f;
    if (tid < 100) p = ws[WS_H + t * 100 + tid] * w_out[tok * 100 + tid];
    sd[tid] = p; __syncthreads();
    for (int st = 128; st > 0; st >>= 1) {
        if (tid < st) sd[tid] += sd[tid + st];
        __syncthreads();
    }
    if (tid == 0) {
        float logit = sd[0] + b_out[tok];
        float loss = sm[0] + logf(ss[0]) - logit;
        atomicAdd(out, loss);
    }
}

extern "C" void kernel_launch(void* const* d_in, const int* in_sizes, int n_in,
                              void* d_out, int out_size, void* d_ws, size_t ws_size,
                              hipStream_t stream) {
    const int*   context = (const int*)d_in[0];
    // d_in[1] = fact_lengths (unused by reference)
    const int*   desc    = (const int*)d_in[2];
    const float* emb_ctx = (const float*)d_in[3];
    const float* emb_dec = (const float*)d_in[4];
    const float* w1      = (const float*)d_in[5];
    const float* b1      = (const float*)d_in[6];
    const float* w_ih    = (const float*)d_in[7];
    const float* w_hh    = (const float*)d_in[8];
    const float* b_ih    = (const float*)d_in[9];
    const float* b_hh    = (const float*)d_in[10];
    const float* w_out   = (const float*)d_in[11];
    const float* b_out   = (const float*)d_in[12];
    float* out = (float*)d_out;
    float* ws  = (float*)d_ws;

    k1_prep  <<<120, 128, 0, stream>>>(context, desc, emb_ctx, emb_dec, ws, out);
    k2_h0_gi <<<160, 320, 0, stream>>>(w1, b1, w_ih, b_ih, ws);
    k3_gru   <<<1,   320, 0, stream>>>(w_hh, b_hh, ws);
    k4_logits<<<256, 256, 0, stream>>>(w_out, b_out, ws);
    k5_final <<<60,  256, 0, stream>>>(desc, w_out, b_out, ws, out);
}